// Round 4
// baseline (652.687 us; speedup 1.0000x reference)
//
#include <hip/hip_runtime.h>
#include <stdint.h>

#define N_NODES 8192
#define DIM 256
#define NHEADS 4
#define DHEAD 64
#define NEDGES 262144
#define NSPLIT 4
#define KSPLIT (N_NODES / NSPLIT)

using bf16x8 = __attribute__((ext_vector_type(8))) __bf16;
using f32x4  = __attribute__((ext_vector_type(4))) float;

__device__ __forceinline__ unsigned short f2b(float f) {
    unsigned int u = __float_as_uint(f);
    unsigned int r = (u + 0x7FFFu + ((u >> 16) & 1u)) >> 16;
    return (unsigned short)r;
}

__device__ __forceinline__ float b2f(unsigned short s) {
    return __uint_as_float((unsigned int)s << 16);
}

__device__ __forceinline__ bf16x8 ld8(const unsigned short* p) {
    return *reinterpret_cast<const bf16x8*>(p);
}

__device__ __forceinline__ f32x4 mf(bf16x8 a, bf16x8 b, f32x4 c) {
    return __builtin_amdgcn_mfma_f32_16x16x32_bf16(a, b, c, 0, 0, 0);
}

// ---------------- dtype detection (int64 vs int32 edge_index) ----------------
__global__ void detect_kernel(const void* edges, int* flag) {
    if (threadIdx.x == 0) {
        const long long* p = (const long long*)edges;
        int ok = 1;
        for (int i = 0; i < 64; ++i) {
            long long v = p[i];
            if (v < 0 || v >= N_NODES) ok = 0;
        }
        *flag = ok;  // 1 => int64 storage, 0 => int32 storage
    }
}

// ---------------- clear bitmask ----------------
__global__ void clear_kernel(uint4* p, int n16) {
    int i = blockIdx.x * blockDim.x + threadIdx.x;
    if (i < n16) p[i] = make_uint4(0, 0, 0, 0);
}

// ---------------- edges -> bitmask ----------------
__global__ void edge_kernel(const void* edges, const int* flag, unsigned* mask) {
    int i = blockIdx.x * blockDim.x + threadIdx.x;
    if (i >= NEDGES) return;
    int src, dst;
    if (*flag) {
        const long long* p = (const long long*)edges;
        src = (int)p[i];
        dst = (int)p[NEDGES + i];
    } else {
        const int* p = (const int*)edges;
        src = p[i];
        dst = p[NEDGES + i];
    }
    atomicOr(&mask[src * (N_NODES / 32) + (dst >> 5)], 1u << (dst & 31));
}

// ---------------- per-row dedup mean aggregation -> bf16 ----------------
__global__ __launch_bounds__(256) void agg_kernel(const unsigned* mask, const float* x,
                                                  unsigned short* m_bf) {
    __shared__ int nbr[N_NODES];
    __shared__ int wsum[4];
    int row = blockIdx.x;
    int tid = threadIdx.x, wave = tid >> 6, lane = tid & 63;

    unsigned bits = mask[row * (N_NODES / 32) + tid];
    int cnt = __popc(bits);
    int scan = cnt;
#pragma unroll
    for (int d = 1; d < 64; d <<= 1) {
        int v = __shfl_up(scan, d);
        if (lane >= d) scan += v;
    }
    if (lane == 63) wsum[wave] = scan;
    __syncthreads();
    int base = 0;
    for (int w = 0; w < 4; ++w) {
        int t = wsum[w];
        if (w < wave) base += t;
    }
    int deg = wsum[0] + wsum[1] + wsum[2] + wsum[3];
    int offset = base + scan - cnt;
    int nb = tid * 32;
    unsigned b2 = bits;
    while (b2) {
        int b = __ffs(b2) - 1;
        b2 &= b2 - 1;
        nbr[offset++] = nb + b;
    }
    __syncthreads();

    float a0 = 0.f, a1 = 0.f, a2 = 0.f, a3 = 0.f;
    int j = 0;
    for (; j + 4 <= deg; j += 4) {
        int n0 = nbr[j], n1 = nbr[j + 1], n2 = nbr[j + 2], n3 = nbr[j + 3];
        a0 += x[(size_t)n0 * DIM + tid];
        a1 += x[(size_t)n1 * DIM + tid];
        a2 += x[(size_t)n2 * DIM + tid];
        a3 += x[(size_t)n3 * DIM + tid];
    }
    for (; j < deg; ++j) a0 += x[(size_t)nbr[j] * DIM + tid];
    float acc = (a0 + a1) + (a2 + a3);
    float s = 1.0f / (float)(deg > 0 ? deg : 1);
    m_bf[(size_t)row * DIM + tid] = f2b(acc * s);
}

// ---------------- fp32 -> bf16 weight conversion ----------------
__global__ void cvt_kernel(const float* src, unsigned short* dst, int n) {
    int i = blockIdx.x * blockDim.x + threadIdx.x;
    if (i < n) dst[i] = f2b(src[i]);
}

// ---------------- generic bf16 MFMA GEMM ----------------
template <int K>
__global__ __launch_bounds__(256) void gemm_kernel(const unsigned short* A,
                                                   const unsigned short* W,
                                                   const float* bias, const float* res,
                                                   float* outF, unsigned short* outB,
                                                   int Nout, int qcols, int gelu) {
    int wave = threadIdx.x >> 6, lane = threadIdx.x & 63;
    int lr = lane & 15, lq = lane >> 4;
    int r0 = blockIdx.x * 64 + wave * 16;
    int c0 = blockIdx.y * 64;
    f32x4 acc[4] = {};
    const unsigned short* arow = A + (size_t)(r0 + lr) * K + lq * 8;
#pragma unroll
    for (int kc = 0; kc < K / 32; ++kc) {
        bf16x8 af = ld8(arow + kc * 32);
#pragma unroll
        for (int ct = 0; ct < 4; ++ct) {
            bf16x8 bf = ld8(W + (size_t)(c0 + ct * 16 + lr) * K + kc * 32 + lq * 8);
            acc[ct] = mf(af, bf, acc[ct]);
        }
    }
#pragma unroll
    for (int ct = 0; ct < 4; ++ct) {
        int col = c0 + ct * 16 + lr;
        float bi = bias[col];
#pragma unroll
        for (int r = 0; r < 4; ++r) {
            int row = r0 + lq * 4 + r;
            float g = acc[ct][r] + bi;
            if (gelu) g = 0.5f * g * (1.0f + erff(g * 0.70710678118654752f));
            if (res) g += res[(size_t)row * Nout + col];
            if (outF) outF[(size_t)row * Nout + col] = g;
            if (outB) {
                float gb = (col < qcols) ? g * 0.125f : g;
                outB[(size_t)row * Nout + col] = f2b(gb);
            }
        }
    }
}

// ---------------- V transpose: qkv cols [512..768) -> Vt[h][d][n] ----------------
__global__ __launch_bounds__(256) void vt_kernel(const unsigned short* qkv,
                                                 unsigned short* Vt) {
    __shared__ unsigned short T[64][72];
    int h = blockIdx.y;
    int n0 = blockIdx.x * 64;
    int t = threadIdx.x;
    int r = t & 63, cb = (t >> 6) * 16;
    const unsigned short* src = qkv + (size_t)(n0 + r) * 768 + 512 + h * 64 + cb;
    *(uint4*)&T[r][cb] = *(const uint4*)src;
    *(uint4*)&T[r][cb + 8] = *(const uint4*)(src + 8);
    __syncthreads();
    int d = t >> 2, nb = (t & 3) * 16;
    unsigned short tmp[16];
#pragma unroll
    for (int j = 0; j < 16; ++j) tmp[j] = T[nb + j][d];
    unsigned short* dst = Vt + (size_t)(h * 64 + d) * 8192 + n0 + nb;
    *(uint4*)dst = *(uint4*)&tmp[0];
    *(uint4*)(dst + 8) = *(uint4*)&tmp[8];
}

// ---------------- register-resident flash attention, KV-split ----------------
// blockIdx = (q-tile, head, split). Each split covers KSPLIT keys and writes a
// normalized partial O (bf16) plus per-row (m, l) for the merge pass.
__global__ __launch_bounds__(256, 8) void flash_kernel(const unsigned short* qkv,
                                                       const unsigned short* vt,
                                                       unsigned short* Opart,
                                                       float2* ml) {
    __shared__ unsigned short Ob[4][16][72];
    int h = blockIdx.y;
    int sp = blockIdx.z;
    int tid = threadIdx.x, wave = tid >> 6, lane = tid & 63;
    int c16 = lane & 15, g = lane >> 4;
    int q0 = blockIdx.x * 64 + wave * 16;

    bf16x8 qf[2];
    {
        const unsigned short* qrow = qkv + (size_t)(q0 + c16) * 768 + h * DHEAD;
        qf[0] = ld8(qrow + g * 8);
        qf[1] = ld8(qrow + 32 + g * 8);
    }
    f32x4 O[4] = {};
    float m = -1e30f, l = 0.0f;

    const unsigned short* kbase = qkv + DIM + h * DHEAD;
    const unsigned short* vbase = vt + (size_t)(h * DHEAD) * N_NODES;
    int rowperm = 8 * (c16 >> 2) + (c16 & 3);  // lane-fixed part of key-row permutation

    int k0 = sp * KSPLIT, k1 = k0 + KSPLIT;
    for (int kb = k0; kb < k1; kb += 64) {
        // S^T = K @ Q^T with permuted key rows
        f32x4 S[4];
#pragma unroll
        for (int ct = 0; ct < 4; ++ct) {
            int keyrow = kb + 32 * (ct >> 1) + 4 * (ct & 1) + rowperm;
            const unsigned short* kr = kbase + (size_t)keyrow * 768 + g * 8;
            f32x4 a = {};
            a = mf(ld8(kr), qf[0], a);
            a = mf(ld8(kr + 32), qf[1], a);
            S[ct] = a;
        }

        // online softmax: lane owns q = q0 + c16; keys split across g-groups
        float tm = S[0][0];
#pragma unroll
        for (int ct = 0; ct < 4; ++ct)
#pragma unroll
            for (int r = 0; r < 4; ++r) tm = fmaxf(tm, S[ct][r]);
        tm = fmaxf(tm, __shfl_xor(tm, 16));
        tm = fmaxf(tm, __shfl_xor(tm, 32));
        float mn = fmaxf(m, tm);
        float sc = __expf(m - mn);
        float rs = 0.0f;
#pragma unroll
        for (int ct = 0; ct < 4; ++ct)
#pragma unroll
            for (int r = 0; r < 4; ++r) {
                float pv = __expf(S[ct][r] - mn);
                S[ct][r] = pv;
                rs += pv;
            }
        rs += __shfl_xor(rs, 16);
        rs += __shfl_xor(rs, 32);
        l = l * sc + rs;
        m = mn;
#pragma unroll
        for (int dt = 0; dt < 4; ++dt)
#pragma unroll
            for (int r = 0; r < 4; ++r) O[dt][r] *= sc;

        // pack P (keys 8g..8g+7 / 32+8g..+7 are lane-local by construction)
        bf16x8 pb0, pb1;
#pragma unroll
        for (int r = 0; r < 4; ++r) {
            pb0[r] = (__bf16)S[0][r];
            pb0[4 + r] = (__bf16)S[1][r];
            pb1[r] = (__bf16)S[2][r];
            pb1[4 + r] = (__bf16)S[3][r];
        }

        // O^T += V^T @ P
#pragma unroll
        for (int dt = 0; dt < 4; ++dt) {
            const unsigned short* vr = vbase + (size_t)(16 * dt + c16) * N_NODES + kb + 8 * g;
            f32x4 o = O[dt];
            o = mf(ld8(vr), pb0, o);
            o = mf(ld8(vr + 32), pb1, o);
            O[dt] = o;
        }
    }

    float inv = 1.0f / l;
#pragma unroll
    for (int dt = 0; dt < 4; ++dt)
#pragma unroll
        for (int r = 0; r < 4; ++r)
            Ob[wave][c16][16 * dt + 4 * g + r] = f2b(O[dt][r] * inv);
    if (g == 0)
        ml[((size_t)sp * N_NODES + q0 + c16) * NHEADS + h] = make_float2(m, l);
    __syncthreads();
    int qr = lane >> 2, nc = (lane & 3) * 16;
    unsigned short* dst = Opart + ((size_t)sp * N_NODES + blockIdx.x * 64 + wave * 16 + qr) * DIM + h * DHEAD + nc;
    *(uint4*)dst = *(uint4*)&Ob[wave][qr][nc];
    *(uint4*)(dst + 8) = *(uint4*)&Ob[wave][qr][nc + 8];
}

// ---------------- merge KV-split partials ----------------
__global__ __launch_bounds__(256) void merge_kernel(const unsigned short* Opart,
                                                    const float2* ml,
                                                    unsigned short* attnb) {
    int row = blockIdx.x;
    int tid = threadIdx.x;  // column 0..255
    int h = tid >> 6;
    float2 e[NSPLIT];
    float M = -1e30f;
#pragma unroll
    for (int s = 0; s < NSPLIT; ++s) {
        e[s] = ml[((size_t)s * N_NODES + row) * NHEADS + h];
        M = fmaxf(M, e[s].x);
    }
    float L = 0.0f, w[NSPLIT];
#pragma unroll
    for (int s = 0; s < NSPLIT; ++s) {
        w[s] = e[s].y * __expf(e[s].x - M);
        L += w[s];
    }
    float invL = 1.0f / L;
    float acc = 0.0f;
#pragma unroll
    for (int s = 0; s < NSPLIT; ++s)
        acc += w[s] * b2f(Opart[((size_t)s * N_NODES + row) * DIM + tid]);
    attnb[(size_t)row * DIM + tid] = f2b(acc * invL);
}

// ---------------- launch ----------------
extern "C" void kernel_launch(void* const* d_in, const int* in_sizes, int n_in,
                              void* d_out, int out_size, void* d_ws, size_t ws_size,
                              hipStream_t stream) {
    const float* x = (const float*)d_in[0];
    const void* edges = d_in[1];
    const float* W_local = (const float*)d_in[2];
    const float* b_local = (const float*)d_in[3];
    const float* W_in = (const float*)d_in[4];
    const float* b_in = (const float*)d_in[5];
    const float* W_out = (const float*)d_in[6];
    const float* b_out = (const float*)d_in[7];
    const float* W1 = (const float*)d_in[8];
    const float* b1 = (const float*)d_in[9];
    const float* W2 = (const float*)d_in[10];
    const float* b2 = (const float*)d_in[11];
    float* out = (float*)d_out;

    char* p = (char*)d_ws;
    size_t off = 0;
    auto take = [&](size_t bytes) { char* q = p + off; off += (bytes + 255) & ~(size_t)255; return q; };
    int* flag = (int*)take(256);
    unsigned* mask = (unsigned*)take((size_t)N_NODES * N_NODES / 8);
    unsigned short* m_bf = (unsigned short*)take((size_t)N_NODES * DIM * 2);
    float* x1 = (float*)take((size_t)N_NODES * DIM * 4);
    unsigned short* x1b = (unsigned short*)take((size_t)N_NODES * DIM * 2);
    unsigned short* qkvb = (unsigned short*)take((size_t)N_NODES * 3 * DIM * 2);
    unsigned short* attnb = (unsigned short*)take((size_t)N_NODES * DIM * 2);
    float* x2 = (float*)take((size_t)N_NODES * DIM * 4);
    unsigned short* x2b = (unsigned short*)take((size_t)N_NODES * DIM * 2);
    unsigned short* hb = (unsigned short*)take((size_t)N_NODES * 2 * DIM * 2);
    unsigned short* Wlb = (unsigned short*)take((size_t)DIM * DIM * 2);
    unsigned short* Winb = (unsigned short*)take((size_t)3 * DIM * DIM * 2);
    unsigned short* Wob = (unsigned short*)take((size_t)DIM * DIM * 2);
    unsigned short* W1b = (unsigned short*)take((size_t)2 * DIM * DIM * 2);
    unsigned short* W2b = (unsigned short*)take((size_t)DIM * 2 * DIM * 2);

    // Aliased scratch (regions dead during attention):
    //   Vt (4 MB) + ml (1 MB) live in mask (8 MB, dead after agg_kernel).
    //   Opart (16 MB, bf16 normalized partials) lives in x2+x2b+hb (20 MB
    //   contiguous, written only after merge_kernel consumed Opart).
    unsigned short* Vtb = (unsigned short*)mask;
    float2* mlbuf = (float2*)((char*)mask + (size_t)4 * 1024 * 1024);
    unsigned short* Opart = (unsigned short*)x2;

    detect_kernel<<<1, 64, 0, stream>>>(edges, flag);
    {
        int n16 = (N_NODES * N_NODES / 8) / 16;
        clear_kernel<<<(n16 + 255) / 256, 256, 0, stream>>>((uint4*)mask, n16);
    }
    edge_kernel<<<(NEDGES + 255) / 256, 256, 0, stream>>>(edges, flag, mask);
    agg_kernel<<<N_NODES, 256, 0, stream>>>(mask, x, m_bf);

    cvt_kernel<<<(DIM * DIM + 255) / 256, 256, 0, stream>>>(W_local, Wlb, DIM * DIM);
    cvt_kernel<<<(3 * DIM * DIM + 255) / 256, 256, 0, stream>>>(W_in, Winb, 3 * DIM * DIM);
    cvt_kernel<<<(DIM * DIM + 255) / 256, 256, 0, stream>>>(W_out, Wob, DIM * DIM);
    cvt_kernel<<<(2 * DIM * DIM + 255) / 256, 256, 0, stream>>>(W1, W1b, 2 * DIM * DIM);
    cvt_kernel<<<(2 * DIM * DIM + 255) / 256, 256, 0, stream>>>(W2, W2b, 2 * DIM * DIM);

    // x1 = x + (m @ W_local^T + b_local)
    gemm_kernel<DIM><<<dim3(N_NODES / 64, DIM / 64), 256, 0, stream>>>(
        m_bf, Wlb, b_local, x, x1, x1b, DIM, 0, 0);
    // qkv = x1 @ W_in^T + b_in  (q cols scaled 1/8 in bf16 copy)
    gemm_kernel<DIM><<<dim3(N_NODES / 64, 3 * DIM / 64), 256, 0, stream>>>(
        x1b, Winb, b_in, nullptr, nullptr, qkvb, 3 * DIM, DIM, 0);
    // V transpose for flash
    vt_kernel<<<dim3(N_NODES / 64, NHEADS), 256, 0, stream>>>(qkvb, Vtb);
    // flash attention, KV-split x4
    flash_kernel<<<dim3(N_NODES / 64, NHEADS, NSPLIT), 256, 0, stream>>>(qkvb, Vtb, Opart, mlbuf);
    // merge partials
    merge_kernel<<<N_NODES, 256, 0, stream>>>(Opart, mlbuf, attnb);
    // x2 = x1 + (attn @ W_out^T + b_out)
    gemm_kernel<DIM><<<dim3(N_NODES / 64, DIM / 64), 256, 0, stream>>>(
        attnb, Wob, b_out, x1, x2, x2b, DIM, 0, 0);
    // h = gelu(x2 @ W1^T + b1)
    gemm_kernel<DIM><<<dim3(N_NODES / 64, 2 * DIM / 64), 256, 0, stream>>>(
        x2b, W1b, b1, nullptr, nullptr, hb, 2 * DIM, 0, 1);
    // out = x2 + (h @ W2^T + b2)
    gemm_kernel<2 * DIM><<<dim3(N_NODES / 64, DIM / 64), 256, 0, stream>>>(
        hb, W2b, b2, x2, out, nullptr, DIM, 0, 0);
}

// Round 6
// 296.289 us; speedup vs baseline: 2.2029x; 2.2029x over previous
//
#include <hip/hip_runtime.h>
#include <stdint.h>

#define N_NODES 8192
#define DIM 256
#define NHEADS 4
#define DHEAD 64
#define NEDGES 262144
#define NSPLIT 4
#define KSPLIT (N_NODES / NSPLIT)

using bf16x8 = __attribute__((ext_vector_type(8))) __bf16;
using f32x4  = __attribute__((ext_vector_type(4))) float;

__device__ __forceinline__ unsigned short f2b(float f) {
    unsigned int u = __float_as_uint(f);
    unsigned int r = (u + 0x7FFFu + ((u >> 16) & 1u)) >> 16;
    return (unsigned short)r;
}

__device__ __forceinline__ float b2f(unsigned short s) {
    return __uint_as_float((unsigned int)s << 16);
}

__device__ __forceinline__ bf16x8 ld8(const unsigned short* p) {
    return *reinterpret_cast<const bf16x8*>(p);
}

__device__ __forceinline__ f32x4 mf(bf16x8 a, bf16x8 b, f32x4 c) {
    return __builtin_amdgcn_mfma_f32_16x16x32_bf16(a, b, c, 0, 0, 0);
}

// async global -> LDS, 16B per lane; LDS dest = uniform base + lane*16
__device__ __forceinline__ void gl16(const void* g, void* l) {
    __builtin_amdgcn_global_load_lds(
        (const __attribute__((address_space(1))) unsigned int*)g,
        (__attribute__((address_space(3))) unsigned int*)l, 16, 0, 0);
}

// ---------------- dtype detection (int64 vs int32 edge_index) ----------------
__global__ void detect_kernel(const void* edges, int* flag) {
    if (threadIdx.x == 0) {
        const long long* p = (const long long*)edges;
        int ok = 1;
        for (int i = 0; i < 64; ++i) {
            long long v = p[i];
            if (v < 0 || v >= N_NODES) ok = 0;
        }
        *flag = ok;  // 1 => int64 storage, 0 => int32 storage
    }
}

// ---------------- clear bitmask ----------------
__global__ void clear_kernel(uint4* p, int n16) {
    int i = blockIdx.x * blockDim.x + threadIdx.x;
    if (i < n16) p[i] = make_uint4(0, 0, 0, 0);
}

// ---------------- edges -> bitmask ----------------
__global__ void edge_kernel(const void* edges, const int* flag, unsigned* mask) {
    int i = blockIdx.x * blockDim.x + threadIdx.x;
    if (i >= NEDGES) return;
    int src, dst;
    if (*flag) {
        const long long* p = (const long long*)edges;
        src = (int)p[i];
        dst = (int)p[NEDGES + i];
    } else {
        const int* p = (const int*)edges;
        src = p[i];
        dst = p[NEDGES + i];
    }
    atomicOr(&mask[src * (N_NODES / 32) + (dst >> 5)], 1u << (dst & 31));
}

// ---------------- per-row dedup mean aggregation -> bf16 ----------------
__global__ __launch_bounds__(256) void agg_kernel(const unsigned* mask, const float* x,
                                                  unsigned short* m_bf) {
    __shared__ int nbr[N_NODES];
    __shared__ int wsum[4];
    int row = blockIdx.x;
    int tid = threadIdx.x, wave = tid >> 6, lane = tid & 63;

    unsigned bits = mask[row * (N_NODES / 32) + tid];
    int cnt = __popc(bits);
    int scan = cnt;
#pragma unroll
    for (int d = 1; d < 64; d <<= 1) {
        int v = __shfl_up(scan, d);
        if (lane >= d) scan += v;
    }
    if (lane == 63) wsum[wave] = scan;
    __syncthreads();
    int base = 0;
    for (int w = 0; w < 4; ++w) {
        int t = wsum[w];
        if (w < wave) base += t;
    }
    int deg = wsum[0] + wsum[1] + wsum[2] + wsum[3];
    int offset = base + scan - cnt;
    int nb = tid * 32;
    unsigned b2 = bits;
    while (b2) {
        int b = __ffs(b2) - 1;
        b2 &= b2 - 1;
        nbr[offset++] = nb + b;
    }
    __syncthreads();

    float a0 = 0.f, a1 = 0.f, a2 = 0.f, a3 = 0.f;
    int j = 0;
    for (; j + 4 <= deg; j += 4) {
        int n0 = nbr[j], n1 = nbr[j + 1], n2 = nbr[j + 2], n3 = nbr[j + 3];
        a0 += x[(size_t)n0 * DIM + tid];
        a1 += x[(size_t)n1 * DIM + tid];
        a2 += x[(size_t)n2 * DIM + tid];
        a3 += x[(size_t)n3 * DIM + tid];
    }
    for (; j < deg; ++j) a0 += x[(size_t)nbr[j] * DIM + tid];
    float acc = (a0 + a1) + (a2 + a3);
    float s = 1.0f / (float)(deg > 0 ? deg : 1);
    m_bf[(size_t)row * DIM + tid] = f2b(acc * s);
}

// ---------------- fp32 -> bf16 weight conversion ----------------
__global__ void cvt_kernel(const float* src, unsigned short* dst, int n) {
    int i = blockIdx.x * blockDim.x + threadIdx.x;
    if (i < n) dst[i] = f2b(src[i]);
}

// ---------------- generic bf16 MFMA GEMM ----------------
template <int K>
__global__ __launch_bounds__(256) void gemm_kernel(const unsigned short* A,
                                                   const unsigned short* W,
                                                   const float* bias, const float* res,
                                                   float* outF, unsigned short* outB,
                                                   int Nout, int qcols, int gelu) {
    int wave = threadIdx.x >> 6, lane = threadIdx.x & 63;
    int lr = lane & 15, lq = lane >> 4;
    int r0 = blockIdx.x * 64 + wave * 16;
    int c0 = blockIdx.y * 64;
    f32x4 acc[4] = {};
    const unsigned short* arow = A + (size_t)(r0 + lr) * K + lq * 8;
#pragma unroll
    for (int kc = 0; kc < K / 32; ++kc) {
        bf16x8 af = ld8(arow + kc * 32);
#pragma unroll
        for (int ct = 0; ct < 4; ++ct) {
            bf16x8 bf = ld8(W + (size_t)(c0 + ct * 16 + lr) * K + kc * 32 + lq * 8);
            acc[ct] = mf(af, bf, acc[ct]);
        }
    }
#pragma unroll
    for (int ct = 0; ct < 4; ++ct) {
        int col = c0 + ct * 16 + lr;
        float bi = bias[col];
#pragma unroll
        for (int r = 0; r < 4; ++r) {
            int row = r0 + lq * 4 + r;
            float g = acc[ct][r] + bi;
            if (gelu) g = 0.5f * g * (1.0f + erff(g * 0.70710678118654752f));
            if (res) g += res[(size_t)row * Nout + col];
            if (outF) outF[(size_t)row * Nout + col] = g;
            if (outB) {
                float gb = (col < qcols) ? g * 0.125f : g;
                outB[(size_t)row * Nout + col] = f2b(gb);
            }
        }
    }
}

// ---------------- V transpose: qkv cols [512..768) -> Vt[h][d][n] ----------------
__global__ __launch_bounds__(256) void vt_kernel(const unsigned short* qkv,
                                                 unsigned short* Vt) {
    __shared__ unsigned short T[64][72];
    int h = blockIdx.y;
    int n0 = blockIdx.x * 64;
    int t = threadIdx.x;
    int r = t & 63, cb = (t >> 6) * 16;
    const unsigned short* src = qkv + (size_t)(n0 + r) * 768 + 512 + h * 64 + cb;
    *(uint4*)&T[r][cb] = *(const uint4*)src;
    *(uint4*)&T[r][cb + 8] = *(const uint4*)(src + 8);
    __syncthreads();
    int d = t >> 2, nb = (t & 3) * 16;
    unsigned short tmp[16];
#pragma unroll
    for (int j = 0; j < 16; ++j) tmp[j] = T[nb + j][d];
    unsigned short* dst = Vt + (size_t)(h * 64 + d) * 8192 + n0 + nb;
    *(uint4*)dst = *(uint4*)&tmp[0];
    *(uint4*)(dst + 8) = *(uint4*)&tmp[8];
}

// ---------------- LDS-staged double-buffered flash attention, KV-split ----------
__global__ __launch_bounds__(256, 4) void flash_kernel(const unsigned short* __restrict__ qkv,
                                                       const unsigned short* __restrict__ vt,
                                                       unsigned short* __restrict__ Opart,
                                                       float2* __restrict__ ml) {
    __shared__ __align__(16) unsigned short smem[16384];  // 32 KB: 2 x (8KB K + 8KB V)
    char* sm = (char*)smem;
    int h = blockIdx.y, sp = blockIdx.z;
    int tid = threadIdx.x, wave = tid >> 6, lane = tid & 63;
    int c16 = lane & 15, g = lane >> 4;
    int q0 = blockIdx.x * 128 + wave * 32;

    // Q fragments (q pre-scaled by 1/8): qf[qg][kc]
    bf16x8 qf[2][2];
#pragma unroll
    for (int qg = 0; qg < 2; ++qg) {
        const unsigned short* qrow = qkv + (size_t)(q0 + qg * 16 + c16) * 768 + h * DHEAD;
#pragma unroll
        for (int kc = 0; kc < 2; ++kc) qf[qg][kc] = ld8(qrow + kc * 32 + g * 8);
    }

    f32x4 O0[4] = {}, O1[4] = {};
    float m0 = -1e30f, m1 = -1e30f, l0 = 0.f, l1 = 0.f;

    // --- per-lane staging source offsets (elements) ---
    int lo3 = lane >> 3;                    // 0..7 = LDS row within 8-row chunk
    int sw = ((lane & 7) ^ lo3) * 8;        // swizzled source slot (elements)
    int KOFFw = 4 * ((wave >> 1) & 1) + 16 * (wave & 1);  // {0,16,4,20}
    int krow = KOFFw + 8 * (lane >> 5) + (lo3 & 3);
    int k0 = sp * KSPLIT;
    const unsigned short* kA = qkv + (size_t)(k0 + krow) * 768 + 256 + h * DHEAD + sw;
    const unsigned short* kB = kA + (size_t)32 * 768;
    const unsigned short* vA = vt + (size_t)(h * DHEAD + 8 * wave + lo3) * N_NODES + k0 + sw;
    const unsigned short* vB = vA + (size_t)32 * N_NODES;
    int ldsKA = wave * 1024, ldsKB = ldsKA + 4096;
    int ldsVA = 8192 + wave * 1024, ldsVB = ldsVA + 4096;

    // per-lane fragment read offsets (bytes)
    int fragrow = c16 * 128;
    int slot0 = ((0 + g) ^ (c16 & 7)) * 16;
    int slot1 = ((4 + g) ^ (c16 & 7)) * 16;

    auto stage = [&](int bufsel) {
        char* b = sm + bufsel * 16384;
        gl16(kA, b + ldsKA);
        gl16(kB, b + ldsKB);
        gl16(vA, b + ldsVA);
        gl16(vB, b + ldsVB);
        kA += 64 * 768; kB += 64 * 768; vA += 64; vB += 64;
    };

    stage(0);
    asm volatile("s_waitcnt vmcnt(0)" ::: "memory");
    __syncthreads();

    const int nt = KSPLIT / 64;
    for (int t = 0; t < nt; ++t) {
        if (t + 1 < nt) stage((t + 1) & 1);
        char* buf = sm + (t & 1) * 16384;

        // S^T = K @ Q^T (keys permuted at store time)
        f32x4 S0[4], S1[4];
#pragma unroll
        for (int ct = 0; ct < 4; ++ct) {
            bf16x8 kf0 = ld8((unsigned short*)(buf + ct * 2048 + fragrow + slot0));
            bf16x8 kf1 = ld8((unsigned short*)(buf + ct * 2048 + fragrow + slot1));
            f32x4 a0 = {}, a1 = {};
            a0 = mf(kf0, qf[0][0], a0);
            a0 = mf(kf1, qf[0][1], a0);
            a1 = mf(kf0, qf[1][0], a1);
            a1 = mf(kf1, qf[1][1], a1);
            S0[ct] = a0;
            S1[ct] = a1;
        }

        // online softmax per q-group (lane owns q = q0 + 16qg + c16)
        {
            float tm = S0[0][0];
#pragma unroll
            for (int ct = 0; ct < 4; ++ct)
#pragma unroll
                for (int r = 0; r < 4; ++r) tm = fmaxf(tm, S0[ct][r]);
            tm = fmaxf(tm, __shfl_xor(tm, 16));
            tm = fmaxf(tm, __shfl_xor(tm, 32));
            float mn = fmaxf(m0, tm);
            float sc = __expf(m0 - mn);
            float rs = 0.0f;
#pragma unroll
            for (int ct = 0; ct < 4; ++ct)
#pragma unroll
                for (int r = 0; r < 4; ++r) {
                    float pv = __expf(S0[ct][r] - mn);
                    S0[ct][r] = pv;
                    rs += pv;
                }
            rs += __shfl_xor(rs, 16);
            rs += __shfl_xor(rs, 32);
            l0 = l0 * sc + rs;
            m0 = mn;
#pragma unroll
            for (int dt = 0; dt < 4; ++dt)
#pragma unroll
                for (int r = 0; r < 4; ++r) O0[dt][r] *= sc;
        }
        {
            float tm = S1[0][0];
#pragma unroll
            for (int ct = 0; ct < 4; ++ct)
#pragma unroll
                for (int r = 0; r < 4; ++r) tm = fmaxf(tm, S1[ct][r]);
            tm = fmaxf(tm, __shfl_xor(tm, 16));
            tm = fmaxf(tm, __shfl_xor(tm, 32));
            float mn = fmaxf(m1, tm);
            float sc = __expf(m1 - mn);
            float rs = 0.0f;
#pragma unroll
            for (int ct = 0; ct < 4; ++ct)
#pragma unroll
                for (int r = 0; r < 4; ++r) {
                    float pv = __expf(S1[ct][r] - mn);
                    S1[ct][r] = pv;
                    rs += pv;
                }
            rs += __shfl_xor(rs, 16);
            rs += __shfl_xor(rs, 32);
            l1 = l1 * sc + rs;
            m1 = mn;
#pragma unroll
            for (int dt = 0; dt < 4; ++dt)
#pragma unroll
                for (int r = 0; r < 4; ++r) O1[dt][r] *= sc;
        }

        // pack P fragments (keys 8g.. / 32+8g.. lane-local by construction)
        bf16x8 p00, p01, p10, p11;
#pragma unroll
        for (int r = 0; r < 4; ++r) {
            p00[r] = (__bf16)S0[0][r]; p00[4 + r] = (__bf16)S0[1][r];
            p01[r] = (__bf16)S0[2][r]; p01[4 + r] = (__bf16)S0[3][r];
            p10[r] = (__bf16)S1[0][r]; p10[4 + r] = (__bf16)S1[1][r];
            p11[r] = (__bf16)S1[2][r]; p11[4 + r] = (__bf16)S1[3][r];
        }

        // O^T += V^T @ P
#pragma unroll
        for (int dt = 0; dt < 4; ++dt) {
            bf16x8 vf0 = ld8((unsigned short*)(buf + 8192 + dt * 2048 + fragrow + slot0));
            bf16x8 vf1 = ld8((unsigned short*)(buf + 8192 + dt * 2048 + fragrow + slot1));
            f32x4 o0 = O0[dt], o1 = O1[dt];
            o0 = mf(vf0, p00, o0);
            o0 = mf(vf1, p01, o0);
            o1 = mf(vf0, p10, o1);
            o1 = mf(vf1, p11, o1);
            O0[dt] = o0;
            O1[dt] = o1;
        }

        asm volatile("s_waitcnt vmcnt(0)" ::: "memory");
        __syncthreads();
    }

    // write (m,l) and bounce O through LDS for coalesced partial store
    float inv0 = 1.0f / l0, inv1 = 1.0f / l1;
    if (g == 0) {
        ml[((size_t)sp * N_NODES + q0 + c16) * NHEADS + h] = make_float2(m0, l0);
        ml[((size_t)sp * N_NODES + q0 + 16 + c16) * NHEADS + h] = make_float2(m1, l1);
    }
    unsigned short* ob = smem + wave * 2304;  // [32 q][72]
#pragma unroll
    for (int dt = 0; dt < 4; ++dt) {
        ushort4 u0, u1;
        u0.x = f2b(O0[dt][0] * inv0); u0.y = f2b(O0[dt][1] * inv0);
        u0.z = f2b(O0[dt][2] * inv0); u0.w = f2b(O0[dt][3] * inv0);
        u1.x = f2b(O1[dt][0] * inv1); u1.y = f2b(O1[dt][1] * inv1);
        u1.z = f2b(O1[dt][2] * inv1); u1.w = f2b(O1[dt][3] * inv1);
        *(ushort4*)&ob[(size_t)c16 * 72 + dt * 16 + 4 * g] = u0;
        *(ushort4*)&ob[(size_t)(16 + c16) * 72 + dt * 16 + 4 * g] = u1;
    }
    __syncthreads();
    {
        int R = tid >> 1, half = tid & 1;
        const unsigned short* src = smem + (R >> 5) * 2304 + (R & 31) * 72 + half * 32;
        unsigned short* dst = Opart + ((size_t)sp * N_NODES + blockIdx.x * 128 + R) * DIM + h * DHEAD + half * 32;
#pragma unroll
        for (int c = 0; c < 4; ++c) {
            uint4 v = *(const uint4*)(src + c * 8);   // 16 B per step (was ushort4: dropped half)
            *(uint4*)(dst + c * 8) = v;
        }
    }
}

// ---------------- merge KV-split partials ----------------
__global__ __launch_bounds__(256) void merge_kernel(const unsigned short* Opart,
                                                    const float2* ml,
                                                    unsigned short* attnb) {
    int row = blockIdx.x;
    int tid = threadIdx.x;  // column 0..255
    int h = tid >> 6;
    float2 e[NSPLIT];
    float M = -1e30f;
#pragma unroll
    for (int s = 0; s < NSPLIT; ++s) {
        e[s] = ml[((size_t)s * N_NODES + row) * NHEADS + h];
        M = fmaxf(M, e[s].x);
    }
    float L = 0.0f, w[NSPLIT];
#pragma unroll
    for (int s = 0; s < NSPLIT; ++s) {
        w[s] = e[s].y * __expf(e[s].x - M);
        L += w[s];
    }
    float invL = 1.0f / L;
    float acc = 0.0f;
#pragma unroll
    for (int s = 0; s < NSPLIT; ++s)
        acc += w[s] * b2f(Opart[((size_t)s * N_NODES + row) * DIM + tid]);
    attnb[(size_t)row * DIM + tid] = f2b(acc * invL);
}

// ---------------- launch ----------------
extern "C" void kernel_launch(void* const* d_in, const int* in_sizes, int n_in,
                              void* d_out, int out_size, void* d_ws, size_t ws_size,
                              hipStream_t stream) {
    const float* x = (const float*)d_in[0];
    const void* edges = d_in[1];
    const float* W_local = (const float*)d_in[2];
    const float* b_local = (const float*)d_in[3];
    const float* W_in = (const float*)d_in[4];
    const float* b_in = (const float*)d_in[5];
    const float* W_out = (const float*)d_in[6];
    const float* b_out = (const float*)d_in[7];
    const float* W1 = (const float*)d_in[8];
    const float* b1 = (const float*)d_in[9];
    const float* W2 = (const float*)d_in[10];
    const float* b2 = (const float*)d_in[11];
    float* out = (float*)d_out;

    char* p = (char*)d_ws;
    size_t off = 0;
    auto take = [&](size_t bytes) { char* q = p + off; off += (bytes + 255) & ~(size_t)255; return q; };
    int* flag = (int*)take(256);
    unsigned* mask = (unsigned*)take((size_t)N_NODES * N_NODES / 8);
    unsigned short* m_bf = (unsigned short*)take((size_t)N_NODES * DIM * 2);
    float* x1 = (float*)take((size_t)N_NODES * DIM * 4);
    unsigned short* x1b = (unsigned short*)take((size_t)N_NODES * DIM * 2);
    unsigned short* qkvb = (unsigned short*)take((size_t)N_NODES * 3 * DIM * 2);
    unsigned short* attnb = (unsigned short*)take((size_t)N_NODES * DIM * 2);
    float* x2 = (float*)take((size_t)N_NODES * DIM * 4);
    unsigned short* x2b = (unsigned short*)take((size_t)N_NODES * DIM * 2);
    unsigned short* hb = (unsigned short*)take((size_t)N_NODES * 2 * DIM * 2);
    unsigned short* Wlb = (unsigned short*)take((size_t)DIM * DIM * 2);
    unsigned short* Winb = (unsigned short*)take((size_t)3 * DIM * DIM * 2);
    unsigned short* Wob = (unsigned short*)take((size_t)DIM * DIM * 2);
    unsigned short* W1b = (unsigned short*)take((size_t)2 * DIM * DIM * 2);
    unsigned short* W2b = (unsigned short*)take((size_t)DIM * 2 * DIM * 2);

    // Aliased scratch (regions dead during attention):
    //   Vt (4 MB) + ml (1 MB) live in mask (8 MB, dead after agg_kernel).
    //   Opart (16 MB bf16 normalized partials) lives in x2+x2b+hb (20 MB).
    unsigned short* Vtb = (unsigned short*)mask;
    float2* mlbuf = (float2*)((char*)mask + (size_t)4 * 1024 * 1024);
    unsigned short* Opart = (unsigned short*)x2;

    detect_kernel<<<1, 64, 0, stream>>>(edges, flag);
    {
        int n16 = (N_NODES * N_NODES / 8) / 16;
        clear_kernel<<<(n16 + 255) / 256, 256, 0, stream>>>((uint4*)mask, n16);
    }
    edge_kernel<<<(NEDGES + 255) / 256, 256, 0, stream>>>(edges, flag, mask);
    agg_kernel<<<N_NODES, 256, 0, stream>>>(mask, x, m_bf);

    cvt_kernel<<<(DIM * DIM + 255) / 256, 256, 0, stream>>>(W_local, Wlb, DIM * DIM);
    cvt_kernel<<<(3 * DIM * DIM + 255) / 256, 256, 0, stream>>>(W_in, Winb, 3 * DIM * DIM);
    cvt_kernel<<<(DIM * DIM + 255) / 256, 256, 0, stream>>>(W_out, Wob, DIM * DIM);
    cvt_kernel<<<(2 * DIM * DIM + 255) / 256, 256, 0, stream>>>(W1, W1b, 2 * DIM * DIM);
    cvt_kernel<<<(2 * DIM * DIM + 255) / 256, 256, 0, stream>>>(W2, W2b, 2 * DIM * DIM);

    // x1 = x + (m @ W_local^T + b_local)
    gemm_kernel<DIM><<<dim3(N_NODES / 64, DIM / 64), 256, 0, stream>>>(
        m_bf, Wlb, b_local, x, x1, x1b, DIM, 0, 0);
    // qkv = x1 @ W_in^T + b_in  (q cols scaled 1/8 in bf16 copy)
    gemm_kernel<DIM><<<dim3(N_NODES / 64, 3 * DIM / 64), 256, 0, stream>>>(
        x1b, Winb, b_in, nullptr, nullptr, qkvb, 3 * DIM, DIM, 0);
    // V transpose for flash
    vt_kernel<<<dim3(N_NODES / 64, NHEADS), 256, 0, stream>>>(qkvb, Vtb);
    // flash attention, KV-split x4 (LDS-staged, double-buffered)
    flash_kernel<<<dim3(N_NODES / 128, NHEADS, NSPLIT), 256, 0, stream>>>(qkvb, Vtb, Opart, mlbuf);
    // merge partials
    merge_kernel<<<N_NODES, 256, 0, stream>>>(Opart, mlbuf, attnb);
    // x2 = x1 + (attn @ W_out^T + b_out)
    gemm_kernel<DIM><<<dim3(N_NODES / 64, DIM / 64), 256, 0, stream>>>(
        attnb, Wob, b_out, x1, x2, x2b, DIM, 0, 0);
    // h = gelu(x2 @ W1^T + b1)
    gemm_kernel<DIM><<<dim3(N_NODES / 64, 2 * DIM / 64), 256, 0, stream>>>(
        x2b, W1b, b1, nullptr, nullptr, hb, 2 * DIM, 0, 1);
    // out = x2 + (h @ W2^T + b2)
    gemm_kernel<2 * DIM><<<dim3(N_NODES / 64, DIM / 64), 256, 0, stream>>>(
        hb, W2b, b2, x2, out, nullptr, DIM, 0, 0);
}

// Round 7
// 229.205 us; speedup vs baseline: 2.8476x; 1.2927x over previous
//
#include <hip/hip_runtime.h>
#include <stdint.h>

#define N_NODES 8192
#define DIM 256
#define NHEADS 4
#define DHEAD 64
#define NEDGES 262144
#define NSPLIT 4
#define KSPLIT (N_NODES / NSPLIT)

using bf16x8 = __attribute__((ext_vector_type(8))) __bf16;
using f32x4  = __attribute__((ext_vector_type(4))) float;

__device__ __forceinline__ unsigned short f2b(float f) {
    unsigned int u = __float_as_uint(f);
    unsigned int r = (u + 0x7FFFu + ((u >> 16) & 1u)) >> 16;
    return (unsigned short)r;
}

__device__ __forceinline__ float b2f(unsigned short s) {
    return __uint_as_float((unsigned int)s << 16);
}

__device__ __forceinline__ bf16x8 ld8(const unsigned short* p) {
    return *reinterpret_cast<const bf16x8*>(p);
}

__device__ __forceinline__ f32x4 mf(bf16x8 a, bf16x8 b, f32x4 c) {
    return __builtin_amdgcn_mfma_f32_16x16x32_bf16(a, b, c, 0, 0, 0);
}

// 2^x in one instruction (v_exp_f32 computes 2^x on CDNA)
__device__ __forceinline__ float fexp2(float x) {
    float r;
    asm volatile("v_exp_f32 %0, %1" : "=v"(r) : "v"(x));
    return r;
}

// async global -> LDS, 16B per lane; LDS dest = wave-uniform base + lane*16
__device__ __forceinline__ void gl16(const void* g, void* l) {
    __builtin_amdgcn_global_load_lds(
        (const __attribute__((address_space(1))) unsigned int*)g,
        (__attribute__((address_space(3))) unsigned int*)l, 16, 0, 0);
}

#define QSCALE 0.18033688f  // 0.125 * log2(e): softmax runs in log2 domain

// ---------------- dtype detection (int64 vs int32 edge_index) ----------------
__global__ void detect_kernel(const void* edges, int* flag) {
    if (threadIdx.x == 0) {
        const long long* p = (const long long*)edges;
        int ok = 1;
        for (int i = 0; i < 64; ++i) {
            long long v = p[i];
            if (v < 0 || v >= N_NODES) ok = 0;
        }
        *flag = ok;  // 1 => int64 storage, 0 => int32 storage
    }
}

// ---------------- clear bitmask ----------------
__global__ void clear_kernel(uint4* p, int n16) {
    int i = blockIdx.x * blockDim.x + threadIdx.x;
    if (i < n16) p[i] = make_uint4(0, 0, 0, 0);
}

// ---------------- edges -> bitmask ----------------
__global__ void edge_kernel(const void* edges, const int* flag, unsigned* mask) {
    int i = blockIdx.x * blockDim.x + threadIdx.x;
    if (i >= NEDGES) return;
    int src, dst;
    if (*flag) {
        const long long* p = (const long long*)edges;
        src = (int)p[i];
        dst = (int)p[NEDGES + i];
    } else {
        const int* p = (const int*)edges;
        src = p[i];
        dst = p[NEDGES + i];
    }
    atomicOr(&mask[src * (N_NODES / 32) + (dst >> 5)], 1u << (dst & 31));
}

// ---------------- per-row dedup mean aggregation -> bf16 ----------------
__global__ __launch_bounds__(256) void agg_kernel(const unsigned* mask, const float* x,
                                                  unsigned short* m_bf) {
    __shared__ int nbr[N_NODES];
    __shared__ int wsum[4];
    int row = blockIdx.x;
    int tid = threadIdx.x, wave = tid >> 6, lane = tid & 63;

    unsigned bits = mask[row * (N_NODES / 32) + tid];
    int cnt = __popc(bits);
    int scan = cnt;
#pragma unroll
    for (int d = 1; d < 64; d <<= 1) {
        int v = __shfl_up(scan, d);
        if (lane >= d) scan += v;
    }
    if (lane == 63) wsum[wave] = scan;
    __syncthreads();
    int base = 0;
    for (int w = 0; w < 4; ++w) {
        int t = wsum[w];
        if (w < wave) base += t;
    }
    int deg = wsum[0] + wsum[1] + wsum[2] + wsum[3];
    int offset = base + scan - cnt;
    int nb = tid * 32;
    unsigned b2 = bits;
    while (b2) {
        int b = __ffs(b2) - 1;
        b2 &= b2 - 1;
        nbr[offset++] = nb + b;
    }
    __syncthreads();

    float a0 = 0.f, a1 = 0.f, a2 = 0.f, a3 = 0.f;
    int j = 0;
    for (; j + 4 <= deg; j += 4) {
        int n0 = nbr[j], n1 = nbr[j + 1], n2 = nbr[j + 2], n3 = nbr[j + 3];
        a0 += x[(size_t)n0 * DIM + tid];
        a1 += x[(size_t)n1 * DIM + tid];
        a2 += x[(size_t)n2 * DIM + tid];
        a3 += x[(size_t)n3 * DIM + tid];
    }
    for (; j < deg; ++j) a0 += x[(size_t)nbr[j] * DIM + tid];
    float acc = (a0 + a1) + (a2 + a3);
    float s = 1.0f / (float)(deg > 0 ? deg : 1);
    m_bf[(size_t)row * DIM + tid] = f2b(acc * s);
}

// ---------------- fp32 -> bf16 weight conversion ----------------
__global__ void cvt_kernel(const float* src, unsigned short* dst, int n) {
    int i = blockIdx.x * blockDim.x + threadIdx.x;
    if (i < n) dst[i] = f2b(src[i]);
}

// ---------------- LDS-staged bf16 MFMA GEMM (m97 pattern) ----------------
// A: M x K bf16 row-major. W: Nout x K bf16 row-major. 64x64 tile, BK=64,
// double-buffered global_load_lds staging, XOR-swizzled conflict-free frags.
template <int K>
__global__ __launch_bounds__(256, 4) void gemm_kernel(const unsigned short* __restrict__ A,
                                                      const unsigned short* __restrict__ W,
                                                      const float* __restrict__ bias,
                                                      const float* __restrict__ res,
                                                      float* __restrict__ outF,
                                                      unsigned short* __restrict__ outB,
                                                      int Nout, int qcols, int gelu) {
    __shared__ __align__(16) char smem[32768];  // 2 bufs x (8KB A + 8KB B)
    int tid = threadIdx.x, wave = tid >> 6, lane = tid & 63;
    int c16 = lane & 15, g = lane >> 4;
    int r0b = blockIdx.x * 64;
    int c0 = blockIdx.y * 64;
    int lo3 = lane >> 3;                   // 0..7: LDS row within 8-row chunk
    int sw = ((lane & 7) ^ lo3) * 8;       // pre-swizzled source column (elems)

    const unsigned short* sA = A + (size_t)(r0b + wave * 8 + lo3) * K + sw;
    const unsigned short* sB = W + (size_t)(c0 + wave * 8 + lo3) * K + sw;
    int dA = wave * 1024;
    int dB = 8192 + wave * 1024;

    auto stage = [&](int kt, int bufsel) {
        char* b = smem + bufsel * 16384;
        const unsigned short* a1 = sA + kt * 64;
        const unsigned short* b1 = sB + kt * 64;
        gl16(a1, b + dA);
        gl16(a1 + (size_t)32 * K, b + dA + 4096);
        gl16(b1, b + dB);
        gl16(b1 + (size_t)32 * K, b + dB + 4096);
    };

    f32x4 acc[4] = {};
    int arow = (wave * 16 + c16) * 128;
    int slot0 = ((0 + g) ^ (c16 & 7)) * 16;  // kc=0
    int slot1 = ((4 + g) ^ (c16 & 7)) * 16;  // kc=1

    stage(0, 0);
    asm volatile("s_waitcnt vmcnt(0)" ::: "memory");
    __syncthreads();

    constexpr int NT = K / 64;
#pragma unroll
    for (int kt = 0; kt < NT; ++kt) {
        if (kt + 1 < NT) stage(kt + 1, (kt + 1) & 1);
        char* buf = smem + (kt & 1) * 16384;
        bf16x8 af0 = ld8((unsigned short*)(buf + arow + slot0));
        bf16x8 af1 = ld8((unsigned short*)(buf + arow + slot1));
#pragma unroll
        for (int ct = 0; ct < 4; ++ct) {
            int brow = (ct * 16 + c16) * 128;
            bf16x8 bf0 = ld8((unsigned short*)(buf + 8192 + brow + slot0));
            bf16x8 bf1 = ld8((unsigned short*)(buf + 8192 + brow + slot1));
            acc[ct] = mf(af0, bf0, acc[ct]);
            acc[ct] = mf(af1, bf1, acc[ct]);
        }
        asm volatile("s_waitcnt vmcnt(0)" ::: "memory");
        __syncthreads();
    }

    int r0 = r0b + wave * 16;
#pragma unroll
    for (int ct = 0; ct < 4; ++ct) {
        int col = c0 + ct * 16 + c16;
        float bi = bias[col];
#pragma unroll
        for (int r = 0; r < 4; ++r) {
            int row = r0 + g * 4 + r;
            float gg = acc[ct][r] + bi;
            if (gelu) gg = 0.5f * gg * (1.0f + erff(gg * 0.70710678118654752f));
            if (res) gg += res[(size_t)row * Nout + col];
            if (outF) outF[(size_t)row * Nout + col] = gg;
            if (outB) {
                float gb = (col < qcols) ? gg * QSCALE : gg;
                outB[(size_t)row * Nout + col] = f2b(gb);
            }
        }
    }
}

// ---------------- V transpose: qkv cols [512..768) -> Vt[h][d][n] ----------------
__global__ __launch_bounds__(256) void vt_kernel(const unsigned short* qkv,
                                                 unsigned short* Vt) {
    __shared__ unsigned short T[64][72];
    int h = blockIdx.y;
    int n0 = blockIdx.x * 64;
    int t = threadIdx.x;
    int r = t & 63, cb = (t >> 6) * 16;
    const unsigned short* src = qkv + (size_t)(n0 + r) * 768 + 512 + h * 64 + cb;
    *(uint4*)&T[r][cb] = *(const uint4*)src;
    *(uint4*)&T[r][cb + 8] = *(const uint4*)(src + 8);
    __syncthreads();
    int d = t >> 2, nb = (t & 3) * 16;
    unsigned short tmp[16];
#pragma unroll
    for (int j = 0; j < 16; ++j) tmp[j] = T[nb + j][d];
    unsigned short* dst = Vt + (size_t)(h * 64 + d) * 8192 + n0 + nb;
    *(uint4*)dst = *(uint4*)&tmp[0];
    *(uint4*)(dst + 8) = *(uint4*)&tmp[8];
}

// ---------------- LDS-staged double-buffered flash attention, KV-split ----------
__global__ __launch_bounds__(256, 4) void flash_kernel(const unsigned short* __restrict__ qkv,
                                                       const unsigned short* __restrict__ vt,
                                                       unsigned short* __restrict__ Opart,
                                                       float2* __restrict__ ml) {
    __shared__ __align__(16) unsigned short smem[16384];  // 32 KB: 2 x (8KB K + 8KB V)
    char* sm = (char*)smem;
    int h = blockIdx.y, sp = blockIdx.z;
    int tid = threadIdx.x, wave = tid >> 6, lane = tid & 63;
    int c16 = lane & 15, g = lane >> 4;
    int q0 = blockIdx.x * 128 + wave * 32;

    // Q fragments (q pre-scaled by 0.125*log2e): qf[qg][kc]
    bf16x8 qf[2][2];
#pragma unroll
    for (int qg = 0; qg < 2; ++qg) {
        const unsigned short* qrow = qkv + (size_t)(q0 + qg * 16 + c16) * 768 + h * DHEAD;
#pragma unroll
        for (int kc = 0; kc < 2; ++kc) qf[qg][kc] = ld8(qrow + kc * 32 + g * 8);
    }

    f32x4 O0[4] = {}, O1[4] = {};
    float m0 = -1e30f, m1 = -1e30f, l0 = 0.f, l1 = 0.f;

    int lo3 = lane >> 3;
    int sw = ((lane & 7) ^ lo3) * 8;
    int KOFFw = 4 * ((wave >> 1) & 1) + 16 * (wave & 1);  // {0,16,4,20}
    int krow = KOFFw + 8 * (lane >> 5) + (lo3 & 3);
    int k0 = sp * KSPLIT;
    const unsigned short* kA = qkv + (size_t)(k0 + krow) * 768 + 256 + h * DHEAD + sw;
    const unsigned short* kB = kA + (size_t)32 * 768;
    const unsigned short* vA = vt + (size_t)(h * DHEAD + 8 * wave + lo3) * N_NODES + k0 + sw;
    const unsigned short* vB = vA + (size_t)32 * N_NODES;
    int ldsKA = wave * 1024, ldsKB = ldsKA + 4096;
    int ldsVA = 8192 + wave * 1024, ldsVB = ldsVA + 4096;

    int fragrow = c16 * 128;
    int slot0 = ((0 + g) ^ (c16 & 7)) * 16;
    int slot1 = ((4 + g) ^ (c16 & 7)) * 16;

    auto stage = [&](int bufsel) {
        char* b = sm + bufsel * 16384;
        gl16(kA, b + ldsKA);
        gl16(kB, b + ldsKB);
        gl16(vA, b + ldsVA);
        gl16(vB, b + ldsVB);
        kA += 64 * 768; kB += 64 * 768; vA += 64; vB += 64;
    };

    stage(0);
    asm volatile("s_waitcnt vmcnt(0)" ::: "memory");
    __syncthreads();

    const int nt = KSPLIT / 64;
    for (int t = 0; t < nt; ++t) {
        if (t + 1 < nt) stage((t + 1) & 1);
        char* buf = sm + (t & 1) * 16384;

        // S^T = K @ Q^T (keys permuted at store time); scores in log2 domain
        f32x4 S0[4], S1[4];
#pragma unroll
        for (int ct = 0; ct < 4; ++ct) {
            bf16x8 kf0 = ld8((unsigned short*)(buf + ct * 2048 + fragrow + slot0));
            bf16x8 kf1 = ld8((unsigned short*)(buf + ct * 2048 + fragrow + slot1));
            f32x4 a0 = {}, a1 = {};
            a0 = mf(kf0, qf[0][0], a0);
            a0 = mf(kf1, qf[0][1], a0);
            a1 = mf(kf0, qf[1][0], a1);
            a1 = mf(kf1, qf[1][1], a1);
            S0[ct] = a0;
            S1[ct] = a1;
        }

        // online softmax with defer-max (THR=8 in log2 units)
        {
            float tm = S0[0][0];
#pragma unroll
            for (int ct = 0; ct < 4; ++ct)
#pragma unroll
                for (int r = 0; r < 4; ++r) tm = fmaxf(tm, S0[ct][r]);
            tm = fmaxf(tm, __shfl_xor(tm, 16));
            tm = fmaxf(tm, __shfl_xor(tm, 32));
            if (tm - m0 > 8.0f) {
                float sc = fexp2(m0 - tm);
                m0 = tm;
                l0 *= sc;
#pragma unroll
                for (int dt = 0; dt < 4; ++dt)
#pragma unroll
                    for (int r = 0; r < 4; ++r) O0[dt][r] *= sc;
            }
            float rs = 0.0f;
#pragma unroll
            for (int ct = 0; ct < 4; ++ct)
#pragma unroll
                for (int r = 0; r < 4; ++r) {
                    float pv = fexp2(S0[ct][r] - m0);
                    S0[ct][r] = pv;
                    rs += pv;
                }
            rs += __shfl_xor(rs, 16);
            rs += __shfl_xor(rs, 32);
            l0 += rs;
        }
        {
            float tm = S1[0][0];
#pragma unroll
            for (int ct = 0; ct < 4; ++ct)
#pragma unroll
                for (int r = 0; r < 4; ++r) tm = fmaxf(tm, S1[ct][r]);
            tm = fmaxf(tm, __shfl_xor(tm, 16));
            tm = fmaxf(tm, __shfl_xor(tm, 32));
            if (tm - m1 > 8.0f) {
                float sc = fexp2(m1 - tm);
                m1 = tm;
                l1 *= sc;
#pragma unroll
                for (int dt = 0; dt < 4; ++dt)
#pragma unroll
                    for (int r = 0; r < 4; ++r) O1[dt][r] *= sc;
            }
            float rs = 0.0f;
#pragma unroll
            for (int ct = 0; ct < 4; ++ct)
#pragma unroll
                for (int r = 0; r < 4; ++r) {
                    float pv = fexp2(S1[ct][r] - m1);
                    S1[ct][r] = pv;
                    rs += pv;
                }
            rs += __shfl_xor(rs, 16);
            rs += __shfl_xor(rs, 32);
            l1 += rs;
        }

        // pack P fragments (keys 8g.. / 32+8g.. lane-local by construction)
        bf16x8 p00, p01, p10, p11;
#pragma unroll
        for (int r = 0; r < 4; ++r) {
            p00[r] = (__bf16)S0[0][r]; p00[4 + r] = (__bf16)S0[1][r];
            p01[r] = (__bf16)S0[2][r]; p01[4 + r] = (__bf16)S0[3][r];
            p10[r] = (__bf16)S1[0][r]; p10[4 + r] = (__bf16)S1[1][r];
            p11[r] = (__bf16)S1[2][r]; p11[4 + r] = (__bf16)S1[3][r];
        }

        // O^T += V^T @ P
#pragma unroll
        for (int dt = 0; dt < 4; ++dt) {
            bf16x8 vf0 = ld8((unsigned short*)(buf + 8192 + dt * 2048 + fragrow + slot0));
            bf16x8 vf1 = ld8((unsigned short*)(buf + 8192 + dt * 2048 + fragrow + slot1));
            f32x4 o0 = O0[dt], o1 = O1[dt];
            o0 = mf(vf0, p00, o0);
            o0 = mf(vf1, p01, o0);
            o1 = mf(vf0, p10, o1);
            o1 = mf(vf1, p11, o1);
            O0[dt] = o0;
            O1[dt] = o1;
        }

        asm volatile("s_waitcnt vmcnt(0)" ::: "memory");
        __syncthreads();
    }

    // write (m,l) and bounce O through LDS for coalesced partial store
    float inv0 = 1.0f / l0, inv1 = 1.0f / l1;
    if (g == 0) {
        ml[((size_t)sp * N_NODES + q0 + c16) * NHEADS + h] = make_float2(m0, l0);
        ml[((size_t)sp * N_NODES + q0 + 16 + c16) * NHEADS + h] = make_float2(m1, l1);
    }
    unsigned short* ob = smem + wave * 2304;  // [32 q][72]
#pragma unroll
    for (int dt = 0; dt < 4; ++dt) {
        ushort4 u0, u1;
        u0.x = f2b(O0[dt][0] * inv0); u0.y = f2b(O0[dt][1] * inv0);
        u0.z = f2b(O0[dt][2] * inv0); u0.w = f2b(O0[dt][3] * inv0);
        u1.x = f2b(O1[dt][0] * inv1); u1.y = f2b(O1[dt][1] * inv1);
        u1.z = f2b(O1[dt][2] * inv1); u1.w = f2b(O1[dt][3] * inv1);
        *(ushort4*)&ob[(size_t)c16 * 72 + dt * 16 + 4 * g] = u0;
        *(ushort4*)&ob[(size_t)(16 + c16) * 72 + dt * 16 + 4 * g] = u1;
    }
    __syncthreads();
    {
        int R = tid >> 1, half = tid & 1;
        const unsigned short* src = smem + (R >> 5) * 2304 + (R & 31) * 72 + half * 32;
        unsigned short* dst = Opart + ((size_t)sp * N_NODES + blockIdx.x * 128 + R) * DIM + h * DHEAD + half * 32;
#pragma unroll
        for (int c = 0; c < 4; ++c) {
            uint4 v = *(const uint4*)(src + c * 8);
            *(uint4*)(dst + c * 8) = v;
        }
    }
}

// ---------------- merge KV-split partials (m in log2 units) ----------------
__global__ __launch_bounds__(256) void merge_kernel(const unsigned short* Opart,
                                                    const float2* ml,
                                                    unsigned short* attnb) {
    int row = blockIdx.x;
    int tid = threadIdx.x;  // column 0..255
    int h = tid >> 6;
    float2 e[NSPLIT];
    float M = -1e30f;
#pragma unroll
    for (int s = 0; s < NSPLIT; ++s) {
        e[s] = ml[((size_t)s * N_NODES + row) * NHEADS + h];
        M = fmaxf(M, e[s].x);
    }
    float L = 0.0f, w[NSPLIT];
#pragma unroll
    for (int s = 0; s < NSPLIT; ++s) {
        w[s] = e[s].y * fexp2(e[s].x - M);
        L += w[s];
    }
    float invL = 1.0f / L;
    float acc = 0.0f;
#pragma unroll
    for (int s = 0; s < NSPLIT; ++s)
        acc += w[s] * b2f(Opart[((size_t)s * N_NODES + row) * DIM + tid]);
    attnb[(size_t)row * DIM + tid] = f2b(acc * invL);
}

// ---------------- launch ----------------
extern "C" void kernel_launch(void* const* d_in, const int* in_sizes, int n_in,
                              void* d_out, int out_size, void* d_ws, size_t ws_size,
                              hipStream_t stream) {
    const float* x = (const float*)d_in[0];
    const void* edges = d_in[1];
    const float* W_local = (const float*)d_in[2];
    const float* b_local = (const float*)d_in[3];
    const float* W_in = (const float*)d_in[4];
    const float* b_in = (const float*)d_in[5];
    const float* W_out = (const float*)d_in[6];
    const float* b_out = (const float*)d_in[7];
    const float* W1 = (const float*)d_in[8];
    const float* b1 = (const float*)d_in[9];
    const float* W2 = (const float*)d_in[10];
    const float* b2 = (const float*)d_in[11];
    float* out = (float*)d_out;

    char* p = (char*)d_ws;
    size_t off = 0;
    auto take = [&](size_t bytes) { char* q = p + off; off += (bytes + 255) & ~(size_t)255; return q; };
    int* flag = (int*)take(256);
    unsigned* mask = (unsigned*)take((size_t)N_NODES * N_NODES / 8);
    unsigned short* m_bf = (unsigned short*)take((size_t)N_NODES * DIM * 2);
    float* x1 = (float*)take((size_t)N_NODES * DIM * 4);
    unsigned short* x1b = (unsigned short*)take((size_t)N_NODES * DIM * 2);
    unsigned short* qkvb = (unsigned short*)take((size_t)N_NODES * 3 * DIM * 2);
    unsigned short* attnb = (unsigned short*)take((size_t)N_NODES * DIM * 2);
    float* x2 = (float*)take((size_t)N_NODES * DIM * 4);
    unsigned short* x2b = (unsigned short*)take((size_t)N_NODES * DIM * 2);
    unsigned short* hb = (unsigned short*)take((size_t)N_NODES * 2 * DIM * 2);
    unsigned short* Wlb = (unsigned short*)take((size_t)DIM * DIM * 2);
    unsigned short* Winb = (unsigned short*)take((size_t)3 * DIM * DIM * 2);
    unsigned short* Wob = (unsigned short*)take((size_t)DIM * DIM * 2);
    unsigned short* W1b = (unsigned short*)take((size_t)2 * DIM * DIM * 2);
    unsigned short* W2b = (unsigned short*)take((size_t)DIM * 2 * DIM * 2);

    // Aliased scratch (regions dead during attention):
    //   Vt (4 MB) + ml (1 MB) live in mask (8 MB, dead after agg_kernel).
    //   Opart (16 MB bf16 normalized partials) lives in x2+x2b+hb (20 MB).
    unsigned short* Vtb = (unsigned short*)mask;
    float2* mlbuf = (float2*)((char*)mask + (size_t)4 * 1024 * 1024);
    unsigned short* Opart = (unsigned short*)x2;

    detect_kernel<<<1, 64, 0, stream>>>(edges, flag);
    {
        int n16 = (N_NODES * N_NODES / 8) / 16;
        clear_kernel<<<(n16 + 255) / 256, 256, 0, stream>>>((uint4*)mask, n16);
    }
    edge_kernel<<<(NEDGES + 255) / 256, 256, 0, stream>>>(edges, flag, mask);
    agg_kernel<<<N_NODES, 256, 0, stream>>>(mask, x, m_bf);

    cvt_kernel<<<(DIM * DIM + 255) / 256, 256, 0, stream>>>(W_local, Wlb, DIM * DIM);
    cvt_kernel<<<(3 * DIM * DIM + 255) / 256, 256, 0, stream>>>(W_in, Winb, 3 * DIM * DIM);
    cvt_kernel<<<(DIM * DIM + 255) / 256, 256, 0, stream>>>(W_out, Wob, DIM * DIM);
    cvt_kernel<<<(2 * DIM * DIM + 255) / 256, 256, 0, stream>>>(W1, W1b, 2 * DIM * DIM);
    cvt_kernel<<<(2 * DIM * DIM + 255) / 256, 256, 0, stream>>>(W2, W2b, 2 * DIM * DIM);

    // x1 = x + (m @ W_local^T + b_local)
    gemm_kernel<DIM><<<dim3(N_NODES / 64, DIM / 64), 256, 0, stream>>>(
        m_bf, Wlb, b_local, x, x1, x1b, DIM, 0, 0);
    // qkv = x1 @ W_in^T + b_in  (q cols scaled by 0.125*log2e in bf16 copy)
    gemm_kernel<DIM><<<dim3(N_NODES / 64, 3 * DIM / 64), 256, 0, stream>>>(
        x1b, Winb, b_in, nullptr, nullptr, qkvb, 3 * DIM, DIM, 0);
    // V transpose for flash
    vt_kernel<<<dim3(N_NODES / 64, NHEADS), 256, 0, stream>>>(qkvb, Vtb);
    // flash attention, KV-split x4 (LDS-staged, double-buffered)
    flash_kernel<<<dim3(N_NODES / 128, NHEADS, NSPLIT), 256, 0, stream>>>(qkvb, Vtb, Opart, mlbuf);
    // merge partials
    merge_kernel<<<N_NODES, 256, 0, stream>>>(Opart, mlbuf, attnb);
    // x2 = x1 + (attn @ W_out^T + b_out)
    gemm_kernel<DIM><<<dim3(N_NODES / 64, DIM / 64), 256, 0, stream>>>(
        attnb, Wob, b_out, x1, x2, x2b, DIM, 0, 0);
    // h = gelu(x2 @ W1^T + b1)
    gemm_kernel<DIM><<<dim3(N_NODES / 64, 2 * DIM / 64), 256, 0, stream>>>(
        x2b, W1b, b1, nullptr, nullptr, hb, 2 * DIM, 0, 1);
    // out = x2 + (h @ W2^T + b2)
    gemm_kernel<2 * DIM><<<dim3(N_NODES / 64, DIM / 64), 256, 0, stream>>>(
        hb, W2b, b2, x2, out, nullptr, DIM, 0, 0);
}